// Round 2
// baseline (448.566 us; speedup 1.0000x reference)
//
#include <hip/hip_runtime.h>
#include <math.h>

#define BUCKET_SHIFT 8  // 256 nodes per bucket
#define MAX_BE 832      // max staged edges per sage block (block edge count ~ Poisson(512), 14 sigma)
#define CHUNK 8192      // edges per CSR-build chunk

typedef short s8v __attribute__((ext_vector_type(8)));   // 8 bf16 (4 VGPRs)
typedef float f4v __attribute__((ext_vector_type(4)));   // 4 fp32 acc
typedef unsigned short u16;

__device__ inline u16 f2bf(float f) {  // RNE fp32->bf16
    unsigned u = __float_as_uint(f);
    return (u16)((u + 0x7FFFu + ((u >> 16) & 1u)) >> 16);
}
__device__ inline float bf2f(u16 s) { return __uint_as_float(((unsigned)s) << 16); }
__device__ inline float blo(unsigned v) { return __uint_as_float(v << 16); }
__device__ inline float bhi(unsigned v) { return __uint_as_float(v & 0xffff0000u); }

// ---------------- CSR build (bucketed, no per-node global atomics) ----------------

// Pass 1: per-chunk LDS bucket histogram -> global bucket counts.
__global__ __launch_bounds__(256) void bucket_count_kernel(const int* __restrict__ dst,
                                                           int* __restrict__ bucketCnt,
                                                           int n_edges, int nbuckets) {
    __shared__ int hist[512];
    int tid = threadIdx.x;
    for (int j = tid; j < nbuckets; j += 256) hist[j] = 0;
    __syncthreads();
    int e0 = blockIdx.x * CHUNK;
    int e1 = min(e0 + CHUNK, n_edges);
    for (int e = e0 + tid; e < e1; e += 256)
        atomicAdd(&hist[dst[e] >> BUCKET_SHIFT], 1);
    __syncthreads();
    for (int j = tid; j < nbuckets; j += 256) {
        int c = hist[j];
        if (c > 0) atomicAdd(&bucketCnt[j], c);
    }
}

// Pass 2: one-block parallel exclusive scan of bucket counts -> bucketBase, gcursor.
__global__ __launch_bounds__(512) void scan_buckets_kernel(const int* __restrict__ bucketCnt,
                                                           int* __restrict__ bucketBase,
                                                           int* __restrict__ gcursor,
                                                           int nbuckets) {
    int tid = threadIdx.x;
    int c = (tid < nbuckets) ? bucketCnt[tid] : 0;
    int lane = tid & 63, wave = tid >> 6;
    int v = c;
#pragma unroll
    for (int off = 1; off < 64; off <<= 1) {
        int t = __shfl_up(v, off, 64);
        if (lane >= off) v += t;
    }
    __shared__ int wsum[8], woff[8];
    if (lane == 63) wsum[wave] = v;
    __syncthreads();
    if (tid == 0) {
        int run = 0;
#pragma unroll
        for (int w = 0; w < 8; ++w) { woff[w] = run; run += wsum[w]; }
    }
    __syncthreads();
    int excl = woff[wave] + (v - c);
    if (tid <= nbuckets) bucketBase[tid] = excl;  // tid==nbuckets -> total E
    if (tid < nbuckets) gcursor[tid] = excl;
}

// Pass 3: chunk-per-block; per-bucket contiguous reservations so each block's
// intermediate writes form single-XCD runs. interm = (src << 8) | (dst & 255).
__global__ __launch_bounds__(256) void bucket_scatter_kernel(const int* __restrict__ src,
                                                             const int* __restrict__ dst,
                                                             int* __restrict__ gcursor,
                                                             unsigned* __restrict__ interm,
                                                             int n_edges, int nbuckets) {
    __shared__ int hist[512];
    __shared__ int gbase[512];
    int tid = threadIdx.x;
    for (int j = tid; j < nbuckets; j += 256) hist[j] = 0;
    __syncthreads();
    int e0 = blockIdx.x * CHUNK;
    int e1 = min(e0 + CHUNK, n_edges);
    for (int e = e0 + tid; e < e1; e += 256)
        atomicAdd(&hist[dst[e] >> BUCKET_SHIFT], 1);
    __syncthreads();
    for (int j = tid; j < nbuckets; j += 256) {
        int c = hist[j];
        gbase[j] = c > 0 ? atomicAdd(&gcursor[j], c) : 0;
        hist[j] = 0;
    }
    __syncthreads();
    for (int e = e0 + tid; e < e1; e += 256) {
        int d = dst[e];
        int s = src[e];
        int j = d >> BUCKET_SHIFT;
        int p = atomicAdd(&hist[j], 1);
        interm[gbase[j] + p] = ((unsigned)s << 8) | (unsigned)(d & 255);
    }
}

// Pass 4: one block per bucket. Builds per-node counts (LDS), block-scans them to
// produce rowptr + invd, then scatters src ids into the bucket's contiguous ssrc run.
__global__ __launch_bounds__(256) void bucket_build_kernel(const unsigned* __restrict__ interm,
                                                           const int* __restrict__ bucketBase,
                                                           int* __restrict__ rowptr,
                                                           float* __restrict__ invd,
                                                           int* __restrict__ ssrc, int n_nodes) {
    __shared__ int cnt[256];
    __shared__ int cur[256];
    __shared__ int wsum[4], woff[4];
    int tid = threadIdx.x;
    int nb0 = blockIdx.x << BUCKET_SHIFT;
    int base = bucketBase[blockIdx.x];
    int end = bucketBase[blockIdx.x + 1];
    cnt[tid] = 0;
    __syncthreads();
    for (int e = base + tid; e < end; e += 256)
        atomicAdd(&cnt[interm[e] & 255u], 1);
    __syncthreads();
    int c = cnt[tid];
    int lane = tid & 63, wave = tid >> 6;
    int v = c;
#pragma unroll
    for (int off = 1; off < 64; off <<= 1) {
        int t = __shfl_up(v, off, 64);
        if (lane >= off) v += t;
    }
    if (lane == 63) wsum[wave] = v;
    __syncthreads();
    if (tid == 0) {
        int run = 0;
#pragma unroll
        for (int w = 0; w < 4; ++w) { woff[w] = run; run += wsum[w]; }
    }
    __syncthreads();
    int excl = woff[wave] + (v - c);
    int node = nb0 + tid;
    if (node < n_nodes) {
        rowptr[node] = base + excl;
        invd[node] = c > 0 ? 1.0f / (float)c : 0.0f;
        if (node == n_nodes - 1) rowptr[n_nodes] = base + excl + c;
    }
    cur[tid] = base + excl;
    __syncthreads();
    for (int e = base + tid; e < end; e += 256) {
        unsigned p = interm[e];
        int pos = atomicAdd(&cur[p & 255u], 1);
        ssrc[pos] = (int)(p >> 8);
    }
}

// ---------------- x -> bf16 ----------------
__global__ __launch_bounds__(256) void convert_kernel(const float* __restrict__ x,
                                                      u16* __restrict__ xb, long total8) {
    long i = (long)blockIdx.x * 256 + threadIdx.x;
    if (i >= total8) return;
    const float* p = &x[i * 8];
    float4 lo = *(const float4*)p;
    float4 hi = *(const float4*)(p + 4);
    union { u16 u[8]; s8v v; } t;
    t.u[0] = f2bf(lo.x); t.u[1] = f2bf(lo.y); t.u[2] = f2bf(lo.z); t.u[3] = f2bf(lo.w);
    t.u[4] = f2bf(hi.x); t.u[5] = f2bf(hi.y); t.u[6] = f2bf(hi.z); t.u[7] = f2bf(hi.w);
    *(s8v*)&xb[i * 8] = t.v;
}

// ---------------- weight packing into MFMA fragment order ----------------
__global__ void pack01_kernel(const float* __restrict__ Wl, const float* __restrict__ Wr,
                              u16* __restrict__ out) {
    int idx = blockIdx.x * 256 + threadIdx.x;  // 256*128
    if (idx >= 32768) return;
    int k = idx >> 7, c = idx & 127;
    float v = (k < 128) ? Wl[k * 128 + c] : Wr[(k - 128) * 128 + c];
    int kt = k >> 5, q = (k >> 3) & 3, j = k & 7, ct = c >> 4, n = c & 15;
    out[(((kt * 8 + ct) * 64 + q * 16 + n) << 3) + j] = f2bf(v);
}

__global__ void packl2_kernel(const float* __restrict__ Wl, const float* __restrict__ Wr,
                              u16* __restrict__ out) {
    int idx = blockIdx.x * 256 + threadIdx.x;  // 128*128
    if (idx >= 16384) return;
    int k = idx >> 7, c = idx & 127;
    float v = 0.f;
    if (c < 47) v = Wl[k * 47 + c];
    else if (c >= 64 && c < 111) v = Wr[k * 47 + (c - 64)];
    int kt = k >> 5, q = (k >> 3) & 3, j = k & 7, ct = c >> 4, n = c & 15;
    out[(((kt * 8 + ct) * 64 + q * 16 + n) << 3) + j] = f2bf(v);
}

// ---------------- fused SAGE layer: LDS edge staging -> gather-agg -> MFMA ----------------
// Gather phase: per 32-lane group, one As row; lanes split 16x16B over the feature row,
// TWO edges per load instruction (half = lane>>4 picks the edge). 8 loads unrolled =
// 16 edges / 8 KB in flight per wave (2x the uint2 scheme). Halves combined once per
// row via shfl_xor(16).
// LDS: As 16896 B + eloc 3328 B + rp 132 B = 20356 -> 20480 rounded -> 8 blocks/CU
// (exactly 160 KiB LDS and the 2048-thread/CU cap) = 32 waves/CU.
#define SAGE_GATHER_STEP(SIDX)                                                            \
    {                                                                                     \
        int s[8];                                                                         \
        uint4 v[8];                                                                       \
        _Pragma("unroll")                                                                 \
        for (int j = 0; j < 8; ++j) s[j] = SIDX(e + 2 * j + half);                        \
        _Pragma("unroll")                                                                 \
        for (int j = 0; j < 8; ++j) v[j] = hin4[(size_t)s[j] * 16 + dd];                  \
        _Pragma("unroll")                                                                 \
        for (int j = 0; j < 8; ++j) {                                                     \
            a[0] += blo(v[j].x); a[1] += bhi(v[j].x);                                     \
            a[2] += blo(v[j].y); a[3] += bhi(v[j].y);                                     \
            a[4] += blo(v[j].z); a[5] += bhi(v[j].z);                                     \
            a[6] += blo(v[j].w); a[7] += bhi(v[j].w);                                     \
        }                                                                                 \
    }

#define SAGE_GATHER_TAIL(SIDX)                                                            \
    for (; e < e1; e += 2) {                                                              \
        int idx = e + half;                                                               \
        if (idx < e1) {                                                                   \
            uint4 v = hin4[(size_t)SIDX(idx) * 16 + dd];                                  \
            a[0] += blo(v.x); a[1] += bhi(v.x);                                           \
            a[2] += blo(v.y); a[3] += bhi(v.y);                                           \
            a[4] += blo(v.z); a[5] += bhi(v.z);                                           \
            a[6] += blo(v.w); a[7] += bhi(v.w);                                           \
        }                                                                                 \
    }

#define ELOC_IDX(i) eloc[i]
#define SSRC_IDX(i) ssrc[base + (i)]

#define SAGE_PROLOGUE()                                                                   \
    __shared__ u16 As[32][264];                                                           \
    __shared__ int eloc[MAX_BE];                                                          \
    __shared__ int rp[33];                                                                \
    int tid = threadIdx.x;                                                                \
    int n0 = blockIdx.x * 32;                                                             \
    if (tid < 33) rp[tid] = rowptr[min(n0 + tid, n_nodes)];                               \
    __syncthreads();                                                                      \
    int base = rp[0];                                                                     \
    int nE = rp[32] - base;                                                               \
    bool staged = nE <= MAX_BE;                                                           \
    if (staged) {                                                                         \
        for (int i = tid; i < nE; i += 256) eloc[i] = ssrc[base + i];                     \
    }                                                                                     \
    __syncthreads();                                                                      \
    int d = tid & 31, grp = tid >> 5;                                                     \
    int half = d >> 4, dd = d & 15;                                                       \
    const uint4* hin4 = (const uint4*)hin2;                                               \
    _Pragma("unroll")                                                                     \
    for (int pass = 0; pass < 4; ++pass) {                                                \
        int row = pass * 8 + grp;                                                         \
        int n = n0 + row;                                                                 \
        float a[8];                                                                       \
        _Pragma("unroll")                                                                 \
        for (int k = 0; k < 8; ++k) a[k] = 0.f;                                           \
        int e = rp[row] - base, e1 = rp[row + 1] - base;                                  \
        if (staged) {                                                                     \
            for (; e + 15 < e1; e += 16) SAGE_GATHER_STEP(ELOC_IDX)                       \
            SAGE_GATHER_TAIL(ELOC_IDX)                                                    \
        } else {                                                                          \
            for (; e + 15 < e1; e += 16) SAGE_GATHER_STEP(SSRC_IDX)                       \
            SAGE_GATHER_TAIL(SSRC_IDX)                                                    \
        }                                                                                 \
        _Pragma("unroll")                                                                 \
        for (int k = 0; k < 8; ++k) a[k] += __shfl_xor(a[k], 16, 64);                     \
        float w = (n < n_nodes) ? invd[n] : 0.f;                                          \
        if (half == 0) {                                                                  \
            union { u16 u[8]; s8v v; } t;                                                 \
            _Pragma("unroll")                                                             \
            for (int k = 0; k < 8; ++k) t.u[k] = f2bf(a[k] * w);                          \
            *(s8v*)&As[row][dd * 8] = t.v;                                                \
        }                                                                                 \
    }                                                                                     \
    const u16* hin = (const u16*)hin2;                                                    \
    for (int i = tid; i < 512; i += 256) {                                                \
        int row = i >> 4, c8 = i & 15;                                                    \
        int n = n0 + row;                                                                 \
        s8v t = (s8v){0, 0, 0, 0, 0, 0, 0, 0};                                            \
        if (n < n_nodes) t = *(const s8v*)&hin[(size_t)n * 128 + c8 * 8];                 \
        *(s8v*)&As[row][128 + c8 * 8] = t;                                                \
    }                                                                                     \
    __syncthreads();                                                                      \
    int wave = tid >> 6, lane = tid & 63;                                                 \
    int rt = wave & 1, ch = wave >> 1;                                                    \
    int m = lane & 15, q = lane >> 4;                                                     \
    f4v acc[4];                                                                           \
    _Pragma("unroll")                                                                     \
    for (int c = 0; c < 4; ++c) acc[c] = (f4v){0.f, 0.f, 0.f, 0.f};                       \
    _Pragma("unroll")                                                                     \
    for (int kt = 0; kt < 8; ++kt) {                                                      \
        s8v a = *(const s8v*)&As[rt * 16 + m][kt * 32 + q * 8];                           \
        _Pragma("unroll")                                                                 \
        for (int c = 0; c < 4; ++c) {                                                     \
            int ctg = ch * 4 + c;                                                         \
            s8v b = *(const s8v*)&Wfrag[(((size_t)kt * 8 + ctg) * 64 + lane) * 8];        \
            acc[c] = __builtin_amdgcn_mfma_f32_16x16x32_bf16(a, b, acc[c], 0, 0, 0);      \
        }                                                                                 \
    }

// hout = relu([mean_agg(hin) | hin] @ Wfrag + b). hin/hout distinct buffers.
__global__ __launch_bounds__(256, 8) void sage_layer_mfma(const uint2* __restrict__ hin2,
                                                          const int* __restrict__ rowptr,
                                                          const int* __restrict__ ssrc,
                                                          const float* __restrict__ invd,
                                                          const u16* __restrict__ Wfrag,
                                                          const float* __restrict__ bias,
                                                          u16* __restrict__ hout, int n_nodes) {
    SAGE_PROLOGUE()

#pragma unroll
    for (int c = 0; c < 4; ++c) {
        int col = ch * 64 + c * 16 + m;
        float bc = bias[col];
#pragma unroll
        for (int r = 0; r < 4; ++r) {
            int n = n0 + rt * 16 + q * 4 + r;
            if (n < n_nodes)
                hout[(size_t)n * 128 + col] = f2bf(fmaxf(acc[c][r] + bc, 0.f));
        }
    }
}

// Fused final sage layer + layer-2 projection: h2 tile stays in LDS, never hits HBM.
// Writes Gn = h2 @ Wl2-frag (cols 0..63) and Gs = h2 @ Wr2-frag (cols 64..127).
__global__ __launch_bounds__(256, 8) void sage_layer_mfma_g(const uint2* __restrict__ hin2,
                                                            const int* __restrict__ rowptr,
                                                            const int* __restrict__ ssrc,
                                                            const float* __restrict__ invd,
                                                            const u16* __restrict__ Wfrag,
                                                            const float* __restrict__ bias,
                                                            const u16* __restrict__ Wfrag2,
                                                            u16* __restrict__ Gn,
                                                            u16* __restrict__ Gs, int n_nodes) {
    SAGE_PROLOGUE()

    // stage-1 epilogue: relu+bias -> h2 tile back into As cols 0..127 (bf16)
    __syncthreads();  // all waves done reading As stage-1 fragments
#pragma unroll
    for (int c = 0; c < 4; ++c) {
        int col = ch * 64 + c * 16 + m;
        float bc = bias[col];
#pragma unroll
        for (int r = 0; r < 4; ++r) {
            int row = rt * 16 + q * 4 + r;
            As[row][col] = f2bf(fmaxf(acc[c][r] + bc, 0.f));
        }
    }
    __syncthreads();

    // stage 2: [Gn|Gs] = h2 @ Wfrag2, K=128
    f4v acc2[4];
#pragma unroll
    for (int c = 0; c < 4; ++c) acc2[c] = (f4v){0.f, 0.f, 0.f, 0.f};
#pragma unroll
    for (int kt = 0; kt < 4; ++kt) {
        s8v a = *(const s8v*)&As[rt * 16 + m][kt * 32 + q * 8];
#pragma unroll
        for (int c = 0; c < 4; ++c) {
            int ctg = ch * 4 + c;
            s8v b = *(const s8v*)&Wfrag2[(((size_t)kt * 8 + ctg) * 64 + lane) * 8];
            acc2[c] = __builtin_amdgcn_mfma_f32_16x16x32_bf16(a, b, acc2[c], 0, 0, 0);
        }
    }

    u16* Gbase = (ch == 0) ? Gn : Gs;
#pragma unroll
    for (int c = 0; c < 4; ++c) {
        int col = c * 16 + m;
#pragma unroll
        for (int r = 0; r < 4; ++r) {
            int n = n0 + rt * 16 + q * 4 + r;
            if (n < n_nodes) Gbase[(size_t)n * 64 + col] = f2bf(acc2[c][r]);
        }
    }
}

// ---------------- layer-2 epilogue: gather Gn + log_softmax ----------------
// Two edges per load instruction: lanes 0..31 edge e, lanes 32..63 edge e+1, each lane
// reading one uint (2 bf16 cols). Combined once per node via shfl_xor(32).
__global__ __launch_bounds__(256) void out_kernel(const u16* __restrict__ Gn,
                                                  const u16* __restrict__ Gs,
                                                  const int* __restrict__ rowptr,
                                                  const int* __restrict__ ssrc,
                                                  const float* __restrict__ inv_deg,
                                                  const float* __restrict__ bias,
                                                  float* __restrict__ out, int n_nodes) {
    int lane = threadIdx.x & 63;
    int n = blockIdx.x * 4 + (threadIdx.x >> 6);
    if (n >= n_nodes) return;
    int half = lane >> 5;   // edge parity
    int c = lane & 31;      // uint column (cols 2c, 2c+1)
    const unsigned* Gnu = (const unsigned*)Gn;
    int e0 = rowptr[n], e1 = rowptr[n + 1];
    float a0 = 0.f, a1 = 0.f;
    int e = e0;
    for (; e + 15 < e1; e += 16) {
        int s[8];
#pragma unroll
        for (int j = 0; j < 8; ++j) s[j] = ssrc[e + 2 * j + half];
        unsigned g[8];
#pragma unroll
        for (int j = 0; j < 8; ++j) g[j] = Gnu[(size_t)s[j] * 32 + c];
#pragma unroll
        for (int j = 0; j < 8; ++j) { a0 += blo(g[j]); a1 += bhi(g[j]); }
    }
    for (; e < e1; e += 2) {
        int idx = e + half;
        if (idx < e1) {
            unsigned g = Gnu[(size_t)ssrc[idx] * 32 + c];
            a0 += blo(g); a1 += bhi(g);
        }
    }
    a0 += __shfl_xor(a0, 32, 64);
    a1 += __shfl_xor(a1, 32, 64);

    int col0 = 2 * c, col1 = 2 * c + 1;
    float id = inv_deg[n];
    unsigned gs = ((const unsigned*)Gs)[(size_t)n * 32 + c];
    float v0 = (col0 < 47) ? a0 * id + blo(gs) + bias[col0] : -INFINITY;
    float v1 = (col1 < 47) ? a1 * id + bhi(gs) + bias[col1] : -INFINITY;

    float m = fmaxf(v0, v1);
#pragma unroll
    for (int off = 16; off >= 1; off >>= 1)
        m = fmaxf(m, __shfl_xor(m, off, 64));
    float s = ((col0 < 47) ? __expf(v0 - m) : 0.f) + ((col1 < 47) ? __expf(v1 - m) : 0.f);
#pragma unroll
    for (int off = 16; off >= 1; off >>= 1)
        s += __shfl_xor(s, off, 64);
    float ls = __logf(s);
    if (half == 0) {
        if (col0 < 47) out[(size_t)n * 47 + col0] = v0 - m - ls;
        if (col1 < 47) out[(size_t)n * 47 + col1] = v1 - m - ls;
    }
}

// ---------------- launch ----------------

extern "C" void kernel_launch(void* const* d_in, const int* in_sizes, int n_in,
                              void* d_out, int out_size, void* d_ws, size_t ws_size,
                              hipStream_t stream) {
    const float* x   = (const float*)d_in[0];
    const int*   src = (const int*)d_in[1];
    const int*   dst = (const int*)d_in[2];
    const float* Wl0 = (const float*)d_in[3];
    const float* bl0 = (const float*)d_in[4];
    const float* Wr0 = (const float*)d_in[5];
    const float* Wl1 = (const float*)d_in[6];
    const float* bl1 = (const float*)d_in[7];
    const float* Wr1 = (const float*)d_in[8];
    const float* Wl2 = (const float*)d_in[9];
    const float* bl2 = (const float*)d_in[10];
    const float* Wr2 = (const float*)d_in[11];
    float* out = (float*)d_out;

    int N = in_sizes[0] / 128;
    int E = in_sizes[1];
    int nBuckets = (N + 255) >> BUCKET_SHIFT;

    char* ws = (char*)d_ws;
    size_t off = 0;
    auto alloc = [&](size_t bytes) -> char* {
        char* p = ws + off;
        off += (bytes + 255) & ~(size_t)255;
        return p;
    };
    int*   rowptr = (int*)alloc((size_t)(N + 1) * 4);
    float* invd   = (float*)alloc((size_t)N * 4);
    int*   ssrc   = (int*)alloc((size_t)E * 4);
    u16*   xb     = (u16*)alloc((size_t)N * 128 * 2);   // layer0 in, layer1 out
    u16*   h1     = (u16*)alloc((size_t)N * 128 * 2);   // layer0 out, layer1 in
    u16*   Gn     = (u16*)alloc((size_t)N * 64 * 2);    // neighbor projection (layer 2)
    u16*   Gs     = (u16*)alloc((size_t)N * 64 * 2);    // self projection (layer 2)
    int*   bucketCnt  = (int*)alloc(512 * 4);
    int*   bucketBase = (int*)alloc(520 * 4);
    int*   gcur   = (int*)alloc(512 * 4);
    u16*   wf0    = (u16*)alloc(32768 * 2);
    u16*   wf1    = (u16*)alloc(32768 * 2);
    u16*   wf2    = (u16*)alloc(16384 * 2);

    // interm (E uints = 6.4 MB) aliases Gn+Gs (25.6 MB): consumed by bucket_build
    // long before sage_layer_mfma_g writes Gn/Gs.
    unsigned* interm = (unsigned*)Gn;

    int nChunks = (E + CHUNK - 1) / CHUNK;

    hipMemsetAsync(bucketCnt, 0, 512 * 4, stream);
    bucket_count_kernel<<<nChunks, 256, 0, stream>>>(dst, bucketCnt, E, nBuckets);
    scan_buckets_kernel<<<1, 512, 0, stream>>>(bucketCnt, bucketBase, gcur, nBuckets);
    bucket_scatter_kernel<<<nChunks, 256, 0, stream>>>(src, dst, gcur, interm, E, nBuckets);
    bucket_build_kernel<<<nBuckets, 256, 0, stream>>>(interm, bucketBase, rowptr, invd,
                                                      ssrc, N);
    long total8 = (long)N * 16;  // N*128/8
    convert_kernel<<<(int)((total8 + 255) / 256), 256, 0, stream>>>(x, xb, total8);
    pack01_kernel<<<128, 256, 0, stream>>>(Wl0, Wr0, wf0);
    pack01_kernel<<<128, 256, 0, stream>>>(Wl1, Wr1, wf1);
    packl2_kernel<<<64, 256, 0, stream>>>(Wl2, Wr2, wf2);

    int gemmGrid = (N + 31) / 32;

    // layer 0: xb -> h1 (fused gather-agg + MFMA)
    sage_layer_mfma<<<gemmGrid, 256, 0, stream>>>((const uint2*)xb, rowptr, ssrc, invd,
                                                  wf0, bl0, h1, N);
    // layer 1 + layer-2 projection fused: h1 -> [Gn|Gs], h2 never hits HBM
    sage_layer_mfma_g<<<gemmGrid, 256, 0, stream>>>((const uint2*)h1, rowptr, ssrc, invd,
                                                    wf1, bl1, wf2, Gn, Gs, N);
    // layer 2 epilogue: 64-wide line gather + log_softmax
    out_kernel<<<(N + 3) / 4, 256, 0, stream>>>(Gn, Gs, rowptr, ssrc, invd, bl2, out, N);
}

// Round 3
// 390.378 us; speedup vs baseline: 1.1491x; 1.1491x over previous
//
#include <hip/hip_runtime.h>
#include <math.h>

#define BUCKET_SHIFT 8  // 256 nodes per bucket
#define MAX_BE 832      // max staged edges per sage block (block edge count ~ Poisson(512), 14 sigma)
#define CHUNK 8192      // edges per CSR-build chunk
#define GSTRIDE 48      // Gn/Gs row stride (47 cols used; 96 B rows, -25% vs 64)

typedef short s8v __attribute__((ext_vector_type(8)));   // 8 bf16 (4 VGPRs)
typedef float f4v __attribute__((ext_vector_type(4)));   // 4 fp32 acc
typedef unsigned short u16;

__device__ inline u16 f2bf(float f) {  // RNE fp32->bf16
    unsigned u = __float_as_uint(f);
    return (u16)((u + 0x7FFFu + ((u >> 16) & 1u)) >> 16);
}
__device__ inline float bf2f(u16 s) { return __uint_as_float(((unsigned)s) << 16); }
__device__ inline float blo(unsigned v) { return __uint_as_float(v << 16); }
__device__ inline float bhi(unsigned v) { return __uint_as_float(v & 0xffff0000u); }

// ---------------- CSR build (bucketed, no per-node global atomics) ----------------

// Pass 1: per-chunk LDS bucket histogram -> global bucket counts.
__global__ __launch_bounds__(256) void bucket_count_kernel(const int* __restrict__ dst,
                                                           int* __restrict__ bucketCnt,
                                                           int n_edges, int nbuckets) {
    __shared__ int hist[512];
    int tid = threadIdx.x;
    for (int j = tid; j < nbuckets; j += 256) hist[j] = 0;
    __syncthreads();
    int e0 = blockIdx.x * CHUNK;
    int e1 = min(e0 + CHUNK, n_edges);
    for (int e = e0 + tid; e < e1; e += 256)
        atomicAdd(&hist[dst[e] >> BUCKET_SHIFT], 1);
    __syncthreads();
    for (int j = tid; j < nbuckets; j += 256) {
        int c = hist[j];
        if (c > 0) atomicAdd(&bucketCnt[j], c);
    }
}

// Pass 2: one-block parallel exclusive scan of bucket counts -> bucketBase, gcursor.
__global__ __launch_bounds__(512) void scan_buckets_kernel(const int* __restrict__ bucketCnt,
                                                           int* __restrict__ bucketBase,
                                                           int* __restrict__ gcursor,
                                                           int nbuckets) {
    int tid = threadIdx.x;
    int c = (tid < nbuckets) ? bucketCnt[tid] : 0;
    int lane = tid & 63, wave = tid >> 6;
    int v = c;
#pragma unroll
    for (int off = 1; off < 64; off <<= 1) {
        int t = __shfl_up(v, off, 64);
        if (lane >= off) v += t;
    }
    __shared__ int wsum[8], woff[8];
    if (lane == 63) wsum[wave] = v;
    __syncthreads();
    if (tid == 0) {
        int run = 0;
#pragma unroll
        for (int w = 0; w < 8; ++w) { woff[w] = run; run += wsum[w]; }
    }
    __syncthreads();
    int excl = woff[wave] + (v - c);
    if (tid <= nbuckets) bucketBase[tid] = excl;  // tid==nbuckets -> total E
    if (tid < nbuckets) gcursor[tid] = excl;
}

// Pass 3: chunk-per-block; per-bucket contiguous reservations so each block's
// intermediate writes form single-XCD runs. interm = (src << 8) | (dst & 255).
__global__ __launch_bounds__(256) void bucket_scatter_kernel(const int* __restrict__ src,
                                                             const int* __restrict__ dst,
                                                             int* __restrict__ gcursor,
                                                             unsigned* __restrict__ interm,
                                                             int n_edges, int nbuckets) {
    __shared__ int hist[512];
    __shared__ int gbase[512];
    int tid = threadIdx.x;
    for (int j = tid; j < nbuckets; j += 256) hist[j] = 0;
    __syncthreads();
    int e0 = blockIdx.x * CHUNK;
    int e1 = min(e0 + CHUNK, n_edges);
    for (int e = e0 + tid; e < e1; e += 256)
        atomicAdd(&hist[dst[e] >> BUCKET_SHIFT], 1);
    __syncthreads();
    for (int j = tid; j < nbuckets; j += 256) {
        int c = hist[j];
        gbase[j] = c > 0 ? atomicAdd(&gcursor[j], c) : 0;
        hist[j] = 0;
    }
    __syncthreads();
    for (int e = e0 + tid; e < e1; e += 256) {
        int d = dst[e];
        int s = src[e];
        int j = d >> BUCKET_SHIFT;
        int p = atomicAdd(&hist[j], 1);
        interm[gbase[j] + p] = ((unsigned)s << 8) | (unsigned)(d & 255);
    }
}

// Pass 4: one block per bucket. Builds per-node counts (LDS), block-scans them to
// produce rowptr + invd, then scatters src ids into the bucket's contiguous ssrc run.
__global__ __launch_bounds__(256) void bucket_build_kernel(const unsigned* __restrict__ interm,
                                                           const int* __restrict__ bucketBase,
                                                           int* __restrict__ rowptr,
                                                           float* __restrict__ invd,
                                                           int* __restrict__ ssrc, int n_nodes) {
    __shared__ int cnt[256];
    __shared__ int cur[256];
    __shared__ int wsum[4], woff[4];
    int tid = threadIdx.x;
    int nb0 = blockIdx.x << BUCKET_SHIFT;
    int base = bucketBase[blockIdx.x];
    int end = bucketBase[blockIdx.x + 1];
    cnt[tid] = 0;
    __syncthreads();
    for (int e = base + tid; e < end; e += 256)
        atomicAdd(&cnt[interm[e] & 255u], 1);
    __syncthreads();
    int c = cnt[tid];
    int lane = tid & 63, wave = tid >> 6;
    int v = c;
#pragma unroll
    for (int off = 1; off < 64; off <<= 1) {
        int t = __shfl_up(v, off, 64);
        if (lane >= off) v += t;
    }
    if (lane == 63) wsum[wave] = v;
    __syncthreads();
    if (tid == 0) {
        int run = 0;
#pragma unroll
        for (int w = 0; w < 4; ++w) { woff[w] = run; run += wsum[w]; }
    }
    __syncthreads();
    int excl = woff[wave] + (v - c);
    int node = nb0 + tid;
    if (node < n_nodes) {
        rowptr[node] = base + excl;
        invd[node] = c > 0 ? 1.0f / (float)c : 0.0f;
        if (node == n_nodes - 1) rowptr[n_nodes] = base + excl + c;
    }
    cur[tid] = base + excl;
    __syncthreads();
    for (int e = base + tid; e < end; e += 256) {
        unsigned p = interm[e];
        int pos = atomicAdd(&cur[p & 255u], 1);
        ssrc[pos] = (int)(p >> 8);
    }
}

// ---------------- x -> bf16 ----------------
__global__ __launch_bounds__(256) void convert_kernel(const float* __restrict__ x,
                                                      u16* __restrict__ xb, long total8) {
    long i = (long)blockIdx.x * 256 + threadIdx.x;
    if (i >= total8) return;
    const float* p = &x[i * 8];
    float4 lo = *(const float4*)p;
    float4 hi = *(const float4*)(p + 4);
    union { u16 u[8]; s8v v; } t;
    t.u[0] = f2bf(lo.x); t.u[1] = f2bf(lo.y); t.u[2] = f2bf(lo.z); t.u[3] = f2bf(lo.w);
    t.u[4] = f2bf(hi.x); t.u[5] = f2bf(hi.y); t.u[6] = f2bf(hi.z); t.u[7] = f2bf(hi.w);
    *(s8v*)&xb[i * 8] = t.v;
}

// ---------------- weight packing into MFMA fragment order (single dispatch) ----------------
// blocks 0..127 -> wf0 (Wl0|Wr0), 128..255 -> wf1 (Wl1|Wr1), 256..319 -> wf2 (Wl2|Wr2 padded)
__global__ __launch_bounds__(256) void pack_all_kernel(const float* __restrict__ Wl0,
                                                       const float* __restrict__ Wr0,
                                                       const float* __restrict__ Wl1,
                                                       const float* __restrict__ Wr1,
                                                       const float* __restrict__ Wl2,
                                                       const float* __restrict__ Wr2,
                                                       u16* __restrict__ wf0,
                                                       u16* __restrict__ wf1,
                                                       u16* __restrict__ wf2) {
    int b = blockIdx.x;
    if (b < 256) {
        const float* Wl = (b < 128) ? Wl0 : Wl1;
        const float* Wr = (b < 128) ? Wr0 : Wr1;
        u16* out = (b < 128) ? wf0 : wf1;
        int idx = (b & 127) * 256 + threadIdx.x;  // 256*128
        int k = idx >> 7, c = idx & 127;
        float v = (k < 128) ? Wl[k * 128 + c] : Wr[(k - 128) * 128 + c];
        int kt = k >> 5, q = (k >> 3) & 3, j = k & 7, ct = c >> 4, n = c & 15;
        out[(((kt * 8 + ct) * 64 + q * 16 + n) << 3) + j] = f2bf(v);
    } else {
        int idx = (b - 256) * 256 + threadIdx.x;  // 128*128
        int k = idx >> 7, c = idx & 127;
        float v = 0.f;
        if (c < 47) v = Wl2[k * 47 + c];
        else if (c >= 64 && c < 111) v = Wr2[k * 47 + (c - 64)];
        int kt = k >> 5, q = (k >> 3) & 3, j = k & 7, ct = c >> 4, n = c & 15;
        wf2[(((kt * 8 + ct) * 64 + q * 16 + n) << 3) + j] = f2bf(v);
    }
}

// ---------------- fused SAGE layer: LDS edge staging -> gather-agg -> MFMA ----------------
// Gather: per 32-lane group, one As row per pass; 32 lanes x uint2 (8 B) = one full
// 256 B feature row per load instruction, 8 edges unrolled (4 KB in flight / wave).
// R2 lesson: do NOT split lanes across multiple edges — more concurrent unique rows
// thrashes L2 (FETCH +23%, WRITE 4x).
// LDS: As 16896 B + eloc 3328 B + rp 132 B = 20356 -> 20480 -> 8 blocks/CU
// (exactly 160 KiB LDS and the 2048-thread/CU cap) = 32 waves/CU.
#define SAGE_PROLOGUE()                                                                   \
    __shared__ u16 As[32][264];                                                           \
    __shared__ int eloc[MAX_BE];                                                          \
    __shared__ int rp[33];                                                                \
    int tid = threadIdx.x;                                                                \
    int n0 = blockIdx.x * 32;                                                             \
    if (tid < 33) rp[tid] = rowptr[min(n0 + tid, n_nodes)];                               \
    __syncthreads();                                                                      \
    int base = rp[0];                                                                     \
    int nE = rp[32] - base;                                                               \
    bool staged = nE <= MAX_BE;                                                           \
    if (staged) {                                                                         \
        for (int i = tid; i < nE; i += 256) eloc[i] = ssrc[base + i];                     \
    }                                                                                     \
    __syncthreads();                                                                      \
    int d = tid & 31, grp = tid >> 5;                                                     \
    _Pragma("unroll")                                                                     \
    for (int pass = 0; pass < 4; ++pass) {                                                \
        int row = pass * 8 + grp;                                                         \
        int n = n0 + row;                                                                 \
        float a0 = 0.f, a1 = 0.f, a2 = 0.f, a3 = 0.f;                                     \
        int e = rp[row] - base, e1 = rp[row + 1] - base;                                  \
        if (staged) {                                                                     \
            for (; e + 7 < e1; e += 8) {                                                  \
                int s[8];                                                                 \
                _Pragma("unroll")                                                         \
                for (int j = 0; j < 8; ++j) s[j] = eloc[e + j];                           \
                uint2 vv[8];                                                              \
                _Pragma("unroll")                                                         \
                for (int j = 0; j < 8; ++j) vv[j] = hin2[(size_t)s[j] * 32 + d];          \
                _Pragma("unroll")                                                         \
                for (int j = 0; j < 8; ++j) {                                             \
                    a0 += blo(vv[j].x); a1 += bhi(vv[j].x);                               \
                    a2 += blo(vv[j].y); a3 += bhi(vv[j].y);                               \
                }                                                                         \
            }                                                                             \
            for (; e < e1; ++e) {                                                         \
                uint2 vv = hin2[(size_t)eloc[e] * 32 + d];                                \
                a0 += blo(vv.x); a1 += bhi(vv.x);                                         \
                a2 += blo(vv.y); a3 += bhi(vv.y);                                         \
            }                                                                             \
        } else {                                                                          \
            for (; e + 7 < e1; e += 8) {                                                  \
                int s[8];                                                                 \
                _Pragma("unroll")                                                         \
                for (int j = 0; j < 8; ++j) s[j] = ssrc[base + e + j];                    \
                uint2 vv[8];                                                              \
                _Pragma("unroll")                                                         \
                for (int j = 0; j < 8; ++j) vv[j] = hin2[(size_t)s[j] * 32 + d];          \
                _Pragma("unroll")                                                         \
                for (int j = 0; j < 8; ++j) {                                             \
                    a0 += blo(vv[j].x); a1 += bhi(vv[j].x);                               \
                    a2 += blo(vv[j].y); a3 += bhi(vv[j].y);                               \
                }                                                                         \
            }                                                                             \
            for (; e < e1; ++e) {                                                         \
                uint2 vv = hin2[(size_t)ssrc[base + e] * 32 + d];                         \
                a0 += blo(vv.x); a1 += bhi(vv.x);                                         \
                a2 += blo(vv.y); a3 += bhi(vv.y);                                         \
            }                                                                             \
        }                                                                                 \
        float w = (n < n_nodes) ? invd[n] : 0.f;                                          \
        a0 *= w; a1 *= w; a2 *= w; a3 *= w;                                               \
        uint2 o;                                                                          \
        o.x = (unsigned)f2bf(a0) | ((unsigned)f2bf(a1) << 16);                            \
        o.y = (unsigned)f2bf(a2) | ((unsigned)f2bf(a3) << 16);                            \
        *(uint2*)&As[row][d * 4] = o;                                                     \
    }                                                                                     \
    const u16* hin = (const u16*)hin2;                                                    \
    for (int i = tid; i < 512; i += 256) {                                                \
        int row = i >> 4, c8 = i & 15;                                                    \
        int n = n0 + row;                                                                 \
        s8v t = (s8v){0, 0, 0, 0, 0, 0, 0, 0};                                            \
        if (n < n_nodes) t = *(const s8v*)&hin[(size_t)n * 128 + c8 * 8];                 \
        *(s8v*)&As[row][128 + c8 * 8] = t;                                                \
    }                                                                                     \
    __syncthreads();                                                                      \
    int wave = tid >> 6, lane = tid & 63;                                                 \
    int rt = wave & 1, ch = wave >> 1;                                                    \
    int m = lane & 15, q = lane >> 4;                                                     \
    f4v acc[4];                                                                           \
    _Pragma("unroll")                                                                     \
    for (int c = 0; c < 4; ++c) acc[c] = (f4v){0.f, 0.f, 0.f, 0.f};                       \
    _Pragma("unroll")                                                                     \
    for (int kt = 0; kt < 8; ++kt) {                                                      \
        s8v a = *(const s8v*)&As[rt * 16 + m][kt * 32 + q * 8];                           \
        _Pragma("unroll")                                                                 \
        for (int c = 0; c < 4; ++c) {                                                     \
            int ctg = ch * 4 + c;                                                         \
            s8v b = *(const s8v*)&Wfrag[(((size_t)kt * 8 + ctg) * 64 + lane) * 8];        \
            acc[c] = __builtin_amdgcn_mfma_f32_16x16x32_bf16(a, b, acc[c], 0, 0, 0);      \
        }                                                                                 \
    }

// hout = relu([mean_agg(hin) | hin] @ Wfrag + b). hin/hout distinct buffers.
__global__ __launch_bounds__(256, 8) void sage_layer_mfma(const uint2* __restrict__ hin2,
                                                          const int* __restrict__ rowptr,
                                                          const int* __restrict__ ssrc,
                                                          const float* __restrict__ invd,
                                                          const u16* __restrict__ Wfrag,
                                                          const float* __restrict__ bias,
                                                          u16* __restrict__ hout, int n_nodes) {
    SAGE_PROLOGUE()

#pragma unroll
    for (int c = 0; c < 4; ++c) {
        int col = ch * 64 + c * 16 + m;
        float bc = bias[col];
#pragma unroll
        for (int r = 0; r < 4; ++r) {
            int n = n0 + rt * 16 + q * 4 + r;
            if (n < n_nodes)
                hout[(size_t)n * 128 + col] = f2bf(fmaxf(acc[c][r] + bc, 0.f));
        }
    }
}

// Fused final sage layer + layer-2 projection: h2 tile stays in LDS, never hits HBM.
// Writes Gn = h2 @ Wl2-frag (cols 0..47 of GSTRIDE rows) and Gs = h2 @ Wr2-frag.
__global__ __launch_bounds__(256, 8) void sage_layer_mfma_g(const uint2* __restrict__ hin2,
                                                            const int* __restrict__ rowptr,
                                                            const int* __restrict__ ssrc,
                                                            const float* __restrict__ invd,
                                                            const u16* __restrict__ Wfrag,
                                                            const float* __restrict__ bias,
                                                            const u16* __restrict__ Wfrag2,
                                                            u16* __restrict__ Gn,
                                                            u16* __restrict__ Gs, int n_nodes) {
    SAGE_PROLOGUE()

    // stage-1 epilogue: relu+bias -> h2 tile back into As cols 0..127 (bf16)
    __syncthreads();  // all waves done reading As stage-1 fragments
#pragma unroll
    for (int c = 0; c < 4; ++c) {
        int col = ch * 64 + c * 16 + m;
        float bc = bias[col];
#pragma unroll
        for (int r = 0; r < 4; ++r) {
            int row = rt * 16 + q * 4 + r;
            As[row][col] = f2bf(fmaxf(acc[c][r] + bc, 0.f));
        }
    }
    __syncthreads();

    // stage 2: [Gn|Gs] = h2 @ Wfrag2, K=128
    f4v acc2[4];
#pragma unroll
    for (int c = 0; c < 4; ++c) acc2[c] = (f4v){0.f, 0.f, 0.f, 0.f};
#pragma unroll
    for (int kt = 0; kt < 4; ++kt) {
        s8v a = *(const s8v*)&As[rt * 16 + m][kt * 32 + q * 8];
#pragma unroll
        for (int c = 0; c < 4; ++c) {
            int ctg = ch * 4 + c;
            s8v b = *(const s8v*)&Wfrag2[(((size_t)kt * 8 + ctg) * 64 + lane) * 8];
            acc2[c] = __builtin_amdgcn_mfma_f32_16x16x32_bf16(a, b, acc2[c], 0, 0, 0);
        }
    }

    // only cols 0..47 are kept (47 classes + 1 pad col), GSTRIDE=48 rows
    u16* Gbase = (ch == 0) ? Gn : Gs;
#pragma unroll
    for (int c = 0; c < 3; ++c) {
        int col = c * 16 + m;
#pragma unroll
        for (int r = 0; r < 4; ++r) {
            int n = n0 + rt * 16 + q * 4 + r;
            if (n < n_nodes) Gbase[(size_t)n * GSTRIDE + col] = f2bf(acc2[c][r]);
        }
    }
}

// ---------------- layer-2 epilogue: gather Gn (96 B rows) + log_softmax ----------------
// Two edges per load instruction: lanes 0..31 edge e, lanes 32..63 edge e+1; active
// lanes c<24 each read one uint (cols 2c,2c+1). Halves combined via shfl_xor(32).
__global__ __launch_bounds__(256) void out_kernel(const u16* __restrict__ Gn,
                                                  const u16* __restrict__ Gs,
                                                  const int* __restrict__ rowptr,
                                                  const int* __restrict__ ssrc,
                                                  const float* __restrict__ inv_deg,
                                                  const float* __restrict__ bias,
                                                  float* __restrict__ out, int n_nodes) {
    int lane = threadIdx.x & 63;
    int n = blockIdx.x * 4 + (threadIdx.x >> 6);
    if (n >= n_nodes) return;
    int half = lane >> 5;   // edge parity
    int c = lane & 31;      // uint column (cols 2c, 2c+1), active c<24
    bool act = c < 24;
    const unsigned* Gnu = (const unsigned*)Gn;
    int e0 = rowptr[n], e1 = rowptr[n + 1];
    float a0 = 0.f, a1 = 0.f;
    int e = e0;
    for (; e + 15 < e1; e += 16) {
        int s[8];
#pragma unroll
        for (int j = 0; j < 8; ++j) s[j] = ssrc[e + 2 * j + half];
        unsigned g[8];
#pragma unroll
        for (int j = 0; j < 8; ++j) g[j] = act ? Gnu[(size_t)s[j] * 24 + c] : 0u;
#pragma unroll
        for (int j = 0; j < 8; ++j) { a0 += blo(g[j]); a1 += bhi(g[j]); }
    }
    for (; e < e1; e += 2) {
        int idx = e + half;
        if (idx < e1 && act) {
            unsigned g = Gnu[(size_t)ssrc[idx] * 24 + c];
            a0 += blo(g); a1 += bhi(g);
        }
    }
    a0 += __shfl_xor(a0, 32, 64);
    a1 += __shfl_xor(a1, 32, 64);

    int col0 = 2 * c, col1 = 2 * c + 1;
    float v0 = -INFINITY, v1 = -INFINITY;
    if (act) {
        float id = inv_deg[n];
        unsigned gs = ((const unsigned*)Gs)[(size_t)n * 24 + c];
        if (col0 < 47) v0 = a0 * id + blo(gs) + bias[col0];
        if (col1 < 47) v1 = a1 * id + bhi(gs) + bias[col1];
    }

    float m = fmaxf(v0, v1);
#pragma unroll
    for (int off = 16; off >= 1; off >>= 1)
        m = fmaxf(m, __shfl_xor(m, off, 64));
    float s = ((v0 != -INFINITY) ? __expf(v0 - m) : 0.f) +
              ((v1 != -INFINITY) ? __expf(v1 - m) : 0.f);
#pragma unroll
    for (int off = 16; off >= 1; off >>= 1)
        s += __shfl_xor(s, off, 64);
    float ls = __logf(s);
    if (half == 0 && act) {
        if (col0 < 47) out[(size_t)n * 47 + col0] = v0 - m - ls;
        if (col1 < 47) out[(size_t)n * 47 + col1] = v1 - m - ls;
    }
}

// ---------------- launch ----------------

extern "C" void kernel_launch(void* const* d_in, const int* in_sizes, int n_in,
                              void* d_out, int out_size, void* d_ws, size_t ws_size,
                              hipStream_t stream) {
    const float* x   = (const float*)d_in[0];
    const int*   src = (const int*)d_in[1];
    const int*   dst = (const int*)d_in[2];
    const float* Wl0 = (const float*)d_in[3];
    const float* bl0 = (const float*)d_in[4];
    const float* Wr0 = (const float*)d_in[5];
    const float* Wl1 = (const float*)d_in[6];
    const float* bl1 = (const float*)d_in[7];
    const float* Wr1 = (const float*)d_in[8];
    const float* Wl2 = (const float*)d_in[9];
    const float* bl2 = (const float*)d_in[10];
    const float* Wr2 = (const float*)d_in[11];
    float* out = (float*)d_out;

    int N = in_sizes[0] / 128;
    int E = in_sizes[1];
    int nBuckets = (N + 255) >> BUCKET_SHIFT;

    char* ws = (char*)d_ws;
    size_t off = 0;
    auto alloc = [&](size_t bytes) -> char* {
        char* p = ws + off;
        off += (bytes + 255) & ~(size_t)255;
        return p;
    };
    int*   rowptr = (int*)alloc((size_t)(N + 1) * 4);
    float* invd   = (float*)alloc((size_t)N * 4);
    int*   ssrc   = (int*)alloc((size_t)E * 4);
    u16*   xb     = (u16*)alloc((size_t)N * 128 * 2);   // layer0 in, layer1 out
    u16*   h1     = (u16*)alloc((size_t)N * 128 * 2);   // layer0 out, layer1 in
    u16*   Gn     = (u16*)alloc((size_t)N * GSTRIDE * 2);  // neighbor projection (layer 2)
    u16*   Gs     = (u16*)alloc((size_t)N * GSTRIDE * 2);  // self projection (layer 2)
    int*   bucketCnt  = (int*)alloc(512 * 4);
    int*   bucketBase = (int*)alloc(520 * 4);
    int*   gcur   = (int*)alloc(512 * 4);
    u16*   wf0    = (u16*)alloc(32768 * 2);
    u16*   wf1    = (u16*)alloc(32768 * 2);
    u16*   wf2    = (u16*)alloc(16384 * 2);

    // interm (E uints = 6.4 MB) aliases Gn+Gs (19.2 MB): consumed by bucket_build
    // long before sage_layer_mfma_g writes Gn/Gs.
    unsigned* interm = (unsigned*)Gn;

    int nChunks = (E + CHUNK - 1) / CHUNK;

    hipMemsetAsync(bucketCnt, 0, 512 * 4, stream);
    bucket_count_kernel<<<nChunks, 256, 0, stream>>>(dst, bucketCnt, E, nBuckets);
    scan_buckets_kernel<<<1, 512, 0, stream>>>(bucketCnt, bucketBase, gcur, nBuckets);
    bucket_scatter_kernel<<<nChunks, 256, 0, stream>>>(src, dst, gcur, interm, E, nBuckets);
    bucket_build_kernel<<<nBuckets, 256, 0, stream>>>(interm, bucketBase, rowptr, invd,
                                                      ssrc, N);
    long total8 = (long)N * 16;  // N*128/8
    convert_kernel<<<(int)((total8 + 255) / 256), 256, 0, stream>>>(x, xb, total8);
    pack_all_kernel<<<320, 256, 0, stream>>>(Wl0, Wr0, Wl1, Wr1, Wl2, Wr2, wf0, wf1, wf2);

    int gemmGrid = (N + 31) / 32;

    // layer 0: xb -> h1 (fused gather-agg + MFMA)
    sage_layer_mfma<<<gemmGrid, 256, 0, stream>>>((const uint2*)xb, rowptr, ssrc, invd,
                                                  wf0, bl0, h1, N);
    // layer 1 + layer-2 projection fused: h1 -> [Gn|Gs], h2 never hits HBM
    sage_layer_mfma_g<<<gemmGrid, 256, 0, stream>>>((const uint2*)h1, rowptr, ssrc, invd,
                                                    wf1, bl1, wf2, Gn, Gs, N);
    // layer 2 epilogue: 96 B line gather + log_softmax
    out_kernel<<<(N + 3) / 4, 256, 0, stream>>>(Gn, Gs, rowptr, ssrc, invd, bl2, out, N);
}

// Round 5
// 378.882 us; speedup vs baseline: 1.1839x; 1.0303x over previous
//
#include <hip/hip_runtime.h>
#include <math.h>

#define BUCKET_SHIFT 8  // 256 nodes per bucket
#define MAX_BE 832      // max staged edges per sage block (block edge count ~ Poisson(512), 14 sigma)
#define CHUNK 8192      // edges per CSR-build chunk
#define GSTRIDE 48      // Gn/Gs row stride (47 cols used; 96 B rows, -25% vs 64)

typedef short s8v __attribute__((ext_vector_type(8)));   // 8 bf16 (4 VGPRs)
typedef float f4v __attribute__((ext_vector_type(4)));   // 4 fp32 acc
typedef unsigned short u16;

__device__ inline u16 f2bf(float f) {  // RNE fp32->bf16
    unsigned u = __float_as_uint(f);
    return (u16)((u + 0x7FFFu + ((u >> 16) & 1u)) >> 16);
}
__device__ inline float bf2f(u16 s) { return __uint_as_float(((unsigned)s) << 16); }
__device__ inline float blo(unsigned v) { return __uint_as_float(v << 16); }
__device__ inline float bhi(unsigned v) { return __uint_as_float(v & 0xffff0000u); }

// ---------------- CSR build (bucketed, no per-node global atomics) ----------------

// Pass 1: per-chunk LDS bucket histogram -> global bucket counts.
__global__ __launch_bounds__(256) void bucket_count_kernel(const int* __restrict__ dst,
                                                           int* __restrict__ bucketCnt,
                                                           int n_edges, int nbuckets) {
    __shared__ int hist[512];
    int tid = threadIdx.x;
    for (int j = tid; j < nbuckets; j += 256) hist[j] = 0;
    __syncthreads();
    int e0 = blockIdx.x * CHUNK;
    int e1 = min(e0 + CHUNK, n_edges);
    for (int e = e0 + tid; e < e1; e += 256)
        atomicAdd(&hist[dst[e] >> BUCKET_SHIFT], 1);
    __syncthreads();
    for (int j = tid; j < nbuckets; j += 256) {
        int c = hist[j];
        if (c > 0) atomicAdd(&bucketCnt[j], c);
    }
}

// Pass 2: one-block parallel exclusive scan of bucket counts -> bucketBase, gcursor.
__global__ __launch_bounds__(512) void scan_buckets_kernel(const int* __restrict__ bucketCnt,
                                                           int* __restrict__ bucketBase,
                                                           int* __restrict__ gcursor,
                                                           int nbuckets) {
    int tid = threadIdx.x;
    int c = (tid < nbuckets) ? bucketCnt[tid] : 0;
    int lane = tid & 63, wave = tid >> 6;
    int v = c;
#pragma unroll
    for (int off = 1; off < 64; off <<= 1) {
        int t = __shfl_up(v, off, 64);
        if (lane >= off) v += t;
    }
    __shared__ int wsum[8], woff[8];
    if (lane == 63) wsum[wave] = v;
    __syncthreads();
    if (tid == 0) {
        int run = 0;
#pragma unroll
        for (int w = 0; w < 8; ++w) { woff[w] = run; run += wsum[w]; }
    }
    __syncthreads();
    int excl = woff[wave] + (v - c);
    if (tid <= nbuckets) bucketBase[tid] = excl;  // tid==nbuckets -> total E
    if (tid < nbuckets) gcursor[tid] = excl;
}

// Pass 3: chunk-per-block; per-bucket contiguous reservations so each block's
// intermediate writes form single-XCD runs. interm = (src << 8) | (dst & 255).
__global__ __launch_bounds__(256) void bucket_scatter_kernel(const int* __restrict__ src,
                                                             const int* __restrict__ dst,
                                                             int* __restrict__ gcursor,
                                                             unsigned* __restrict__ interm,
                                                             int n_edges, int nbuckets) {
    __shared__ int hist[512];
    __shared__ int gbase[512];
    int tid = threadIdx.x;
    for (int j = tid; j < nbuckets; j += 256) hist[j] = 0;
    __syncthreads();
    int e0 = blockIdx.x * CHUNK;
    int e1 = min(e0 + CHUNK, n_edges);
    for (int e = e0 + tid; e < e1; e += 256)
        atomicAdd(&hist[dst[e] >> BUCKET_SHIFT], 1);
    __syncthreads();
    for (int j = tid; j < nbuckets; j += 256) {
        int c = hist[j];
        gbase[j] = c > 0 ? atomicAdd(&gcursor[j], c) : 0;
        hist[j] = 0;
    }
    __syncthreads();
    for (int e = e0 + tid; e < e1; e += 256) {
        int d = dst[e];
        int s = src[e];
        int j = d >> BUCKET_SHIFT;
        int p = atomicAdd(&hist[j], 1);
        interm[gbase[j] + p] = ((unsigned)s << 8) | (unsigned)(d & 255);
    }
}

// Pass 4: one block per bucket. Builds per-node counts (LDS), block-scans them to
// produce rowptr + invd, then scatters src ids into the bucket's contiguous ssrc run.
__global__ __launch_bounds__(256) void bucket_build_kernel(const unsigned* __restrict__ interm,
                                                           const int* __restrict__ bucketBase,
                                                           int* __restrict__ rowptr,
                                                           float* __restrict__ invd,
                                                           int* __restrict__ ssrc, int n_nodes) {
    __shared__ int cnt[256];
    __shared__ int cur[256];
    __shared__ int wsum[4], woff[4];
    int tid = threadIdx.x;
    int nb0 = blockIdx.x << BUCKET_SHIFT;
    int base = bucketBase[blockIdx.x];
    int end = bucketBase[blockIdx.x + 1];
    cnt[tid] = 0;
    __syncthreads();
    for (int e = base + tid; e < end; e += 256)
        atomicAdd(&cnt[interm[e] & 255u], 1);
    __syncthreads();
    int c = cnt[tid];
    int lane = tid & 63, wave = tid >> 6;
    int v = c;
#pragma unroll
    for (int off = 1; off < 64; off <<= 1) {
        int t = __shfl_up(v, off, 64);
        if (lane >= off) v += t;
    }
    if (lane == 63) wsum[wave] = v;
    __syncthreads();
    if (tid == 0) {
        int run = 0;
#pragma unroll
        for (int w = 0; w < 4; ++w) { woff[w] = run; run += wsum[w]; }
    }
    __syncthreads();
    int excl = woff[wave] + (v - c);
    int node = nb0 + tid;
    if (node < n_nodes) {
        rowptr[node] = base + excl;
        invd[node] = c > 0 ? 1.0f / (float)c : 0.0f;
        if (node == n_nodes - 1) rowptr[n_nodes] = base + excl + c;
    }
    cur[tid] = base + excl;
    __syncthreads();
    for (int e = base + tid; e < end; e += 256) {
        unsigned p = interm[e];
        int pos = atomicAdd(&cur[p & 255u], 1);
        ssrc[pos] = (int)(p >> 8);
    }
}

// ---------------- x -> bf16 ----------------
__global__ __launch_bounds__(256) void convert_kernel(const float* __restrict__ x,
                                                      u16* __restrict__ xb, long total8) {
    long i = (long)blockIdx.x * 256 + threadIdx.x;
    if (i >= total8) return;
    const float* p = &x[i * 8];
    float4 lo = *(const float4*)p;
    float4 hi = *(const float4*)(p + 4);
    union { u16 u[8]; s8v v; } t;
    t.u[0] = f2bf(lo.x); t.u[1] = f2bf(lo.y); t.u[2] = f2bf(lo.z); t.u[3] = f2bf(lo.w);
    t.u[4] = f2bf(hi.x); t.u[5] = f2bf(hi.y); t.u[6] = f2bf(hi.z); t.u[7] = f2bf(hi.w);
    *(s8v*)&xb[i * 8] = t.v;
}

// ---------------- weight packing into MFMA fragment order (single dispatch) ----------------
// blocks 0..127 -> wf0 (Wl0|Wr0), 128..255 -> wf1 (Wl1|Wr1), 256..319 -> wf2 (Wl2|Wr2 padded)
__global__ __launch_bounds__(256) void pack_all_kernel(const float* __restrict__ Wl0,
                                                       const float* __restrict__ Wr0,
                                                       const float* __restrict__ Wl1,
                                                       const float* __restrict__ Wr1,
                                                       const float* __restrict__ Wl2,
                                                       const float* __restrict__ Wr2,
                                                       u16* __restrict__ wf0,
                                                       u16* __restrict__ wf1,
                                                       u16* __restrict__ wf2) {
    int b = blockIdx.x;
    if (b < 256) {
        const float* Wl = (b < 128) ? Wl0 : Wl1;
        const float* Wr = (b < 128) ? Wr0 : Wr1;
        u16* out = (b < 128) ? wf0 : wf1;
        int idx = (b & 127) * 256 + threadIdx.x;  // 256*128
        int k = idx >> 7, c = idx & 127;
        float v = (k < 128) ? Wl[k * 128 + c] : Wr[(k - 128) * 128 + c];
        int kt = k >> 5, q = (k >> 3) & 3, j = k & 7, ct = c >> 4, n = c & 15;
        out[(((kt * 8 + ct) * 64 + q * 16 + n) << 3) + j] = f2bf(v);
    } else {
        int idx = (b - 256) * 256 + threadIdx.x;  // 128*128
        int k = idx >> 7, c = idx & 127;
        float v = 0.f;
        if (c < 47) v = Wl2[k * 47 + c];
        else if (c >= 64 && c < 111) v = Wr2[k * 47 + (c - 64)];
        int kt = k >> 5, q = (k >> 3) & 3, j = k & 7, ct = c >> 4, n = c & 15;
        wf2[(((kt * 8 + ct) * 64 + q * 16 + n) << 3) + j] = f2bf(v);
    }
}

// ---------------- fused SAGE layer: LDS edge staging -> gather-agg -> MFMA ----------------
// Gather: per 32-lane group, one As row per pass; 32 lanes x uint2 (8 B) = one full
// 256 B feature row per load instruction, 8 edges unrolled (4 KB in flight / wave).
// R2 lesson: do NOT split lanes across multiple edges — more concurrent unique rows
// thrashes L2 (FETCH +23%, WRITE 4x).
// LDS: As 16896 B + eloc 3328 B + rp 132 B = 20356 -> 20480 -> 8 blocks/CU
// (exactly 160 KiB LDS and the 2048-thread/CU cap) = 32 waves/CU.
#define SAGE_PROLOGUE()                                                                   \
    __shared__ u16 As[32][264];                                                           \
    __shared__ int eloc[MAX_BE];                                                          \
    __shared__ int rp[33];                                                                \
    int tid = threadIdx.x;                                                                \
    int n0 = blockIdx.x * 32;                                                             \
    if (tid < 33) rp[tid] = rowptr[min(n0 + tid, n_nodes)];                               \
    __syncthreads();                                                                      \
    int base = rp[0];                                                                     \
    int nE = rp[32] - base;                                                               \
    bool staged = nE <= MAX_BE;                                                           \
    if (staged) {                                                                         \
        for (int i = tid; i < nE; i += 256) eloc[i] = ssrc[base + i];                     \
    }                                                                                     \
    __syncthreads();                                                                      \
    int d = tid & 31, grp = tid >> 5;                                                     \
    _Pragma("unroll")                                                                     \
    for (int pass = 0; pass < 4; ++pass) {                                                \
        int row = pass * 8 + grp;                                                         \
        int n = n0 + row;                                                                 \
        float a0 = 0.f, a1 = 0.f, a2 = 0.f, a3 = 0.f;                                     \
        int e = rp[row] - base, e1 = rp[row + 1] - base;                                  \
        if (staged) {                                                                     \
            for (; e + 7 < e1; e += 8) {                                                  \
                int s[8];                                                                 \
                _Pragma("unroll")                                                         \
                for (int j = 0; j < 8; ++j) s[j] = eloc[e + j];                           \
                uint2 vv[8];                                                              \
                _Pragma("unroll")                                                         \
                for (int j = 0; j < 8; ++j) vv[j] = hin2[(size_t)s[j] * 32 + d];          \
                _Pragma("unroll")                                                         \
                for (int j = 0; j < 8; ++j) {                                             \
                    a0 += blo(vv[j].x); a1 += bhi(vv[j].x);                               \
                    a2 += blo(vv[j].y); a3 += bhi(vv[j].y);                               \
                }                                                                         \
            }                                                                             \
            for (; e < e1; ++e) {                                                         \
                uint2 vv = hin2[(size_t)eloc[e] * 32 + d];                                \
                a0 += blo(vv.x); a1 += bhi(vv.x);                                         \
                a2 += blo(vv.y); a3 += bhi(vv.y);                                         \
            }                                                                             \
        } else {                                                                          \
            for (; e + 7 < e1; e += 8) {                                                  \
                int s[8];                                                                 \
                _Pragma("unroll")                                                         \
                for (int j = 0; j < 8; ++j) s[j] = ssrc[base + e + j];                    \
                uint2 vv[8];                                                              \
                _Pragma("unroll")                                                         \
                for (int j = 0; j < 8; ++j) vv[j] = hin2[(size_t)s[j] * 32 + d];          \
                _Pragma("unroll")                                                         \
                for (int j = 0; j < 8; ++j) {                                             \
                    a0 += blo(vv[j].x); a1 += bhi(vv[j].x);                               \
                    a2 += blo(vv[j].y); a3 += bhi(vv[j].y);                               \
                }                                                                         \
            }                                                                             \
            for (; e < e1; ++e) {                                                         \
                uint2 vv = hin2[(size_t)ssrc[base + e] * 32 + d];                         \
                a0 += blo(vv.x); a1 += bhi(vv.x);                                         \
                a2 += blo(vv.y); a3 += bhi(vv.y);                                         \
            }                                                                             \
        }                                                                                 \
        float w = (n < n_nodes) ? invd[n] : 0.f;                                          \
        a0 *= w; a1 *= w; a2 *= w; a3 *= w;                                               \
        uint2 o;                                                                          \
        o.x = (unsigned)f2bf(a0) | ((unsigned)f2bf(a1) << 16);                            \
        o.y = (unsigned)f2bf(a2) | ((unsigned)f2bf(a3) << 16);                            \
        *(uint2*)&As[row][d * 4] = o;                                                     \
    }                                                                                     \
    const u16* hin = (const u16*)hin2;                                                    \
    for (int i = tid; i < 512; i += 256) {                                                \
        int row = i >> 4, c8 = i & 15;                                                    \
        int n = n0 + row;                                                                 \
        s8v t = (s8v){0, 0, 0, 0, 0, 0, 0, 0};                                            \
        if (n < n_nodes) t = *(const s8v*)&hin[(size_t)n * 128 + c8 * 8];                 \
        *(s8v*)&As[row][128 + c8 * 8] = t;                                                \
    }                                                                                     \
    __syncthreads();                                                                      \
    int wave = tid >> 6, lane = tid & 63;                                                 \
    int rt = wave & 1, ch = wave >> 1;                                                    \
    int m = lane & 15, q = lane >> 4;                                                     \
    f4v acc[4];                                                                           \
    _Pragma("unroll")                                                                     \
    for (int c = 0; c < 4; ++c) acc[c] = (f4v){0.f, 0.f, 0.f, 0.f};                       \
    _Pragma("unroll")                                                                     \
    for (int kt = 0; kt < 8; ++kt) {                                                      \
        s8v a = *(const s8v*)&As[rt * 16 + m][kt * 32 + q * 8];                           \
        _Pragma("unroll")                                                                 \
        for (int c = 0; c < 4; ++c) {                                                     \
            int ctg = ch * 4 + c;                                                         \
            s8v b = *(const s8v*)&Wfrag[(((size_t)kt * 8 + ctg) * 64 + lane) * 8];        \
            acc[c] = __builtin_amdgcn_mfma_f32_16x16x32_bf16(a, b, acc[c], 0, 0, 0);      \
        }                                                                                 \
    }

// hout = relu([mean_agg(hin) | hin] @ Wfrag + b). hin/hout distinct buffers.
__global__ __launch_bounds__(256, 8) void sage_layer_mfma(const uint2* __restrict__ hin2,
                                                          const int* __restrict__ rowptr,
                                                          const int* __restrict__ ssrc,
                                                          const float* __restrict__ invd,
                                                          const u16* __restrict__ Wfrag,
                                                          const float* __restrict__ bias,
                                                          u16* __restrict__ hout, int n_nodes) {
    SAGE_PROLOGUE()

#pragma unroll
    for (int c = 0; c < 4; ++c) {
        int col = ch * 64 + c * 16 + m;
        float bc = bias[col];
#pragma unroll
        for (int r = 0; r < 4; ++r) {
            int n = n0 + rt * 16 + q * 4 + r;
            if (n < n_nodes)
                hout[(size_t)n * 128 + col] = f2bf(fmaxf(acc[c][r] + bc, 0.f));
        }
    }
}

// Fused final sage layer + layer-2 projection: h2 tile stays in LDS, never hits HBM.
// Writes Gn = h2 @ Wl2-frag (cols 0..47 of GSTRIDE rows) and Gs = h2 @ Wr2-frag.
__global__ __launch_bounds__(256, 8) void sage_layer_mfma_g(const uint2* __restrict__ hin2,
                                                            const int* __restrict__ rowptr,
                                                            const int* __restrict__ ssrc,
                                                            const float* __restrict__ invd,
                                                            const u16* __restrict__ Wfrag,
                                                            const float* __restrict__ bias,
                                                            const u16* __restrict__ Wfrag2,
                                                            u16* __restrict__ Gn,
                                                            u16* __restrict__ Gs, int n_nodes) {
    SAGE_PROLOGUE()

    // stage-1 epilogue: relu+bias -> h2 tile back into As cols 0..127 (bf16)
    __syncthreads();  // all waves done reading As stage-1 fragments
#pragma unroll
    for (int c = 0; c < 4; ++c) {
        int col = ch * 64 + c * 16 + m;
        float bc = bias[col];
#pragma unroll
        for (int r = 0; r < 4; ++r) {
            int row = rt * 16 + q * 4 + r;
            As[row][col] = f2bf(fmaxf(acc[c][r] + bc, 0.f));
        }
    }
    __syncthreads();

    // stage 2: [Gn|Gs] = h2 @ Wfrag2, K=128
    f4v acc2[4];
#pragma unroll
    for (int c = 0; c < 4; ++c) acc2[c] = (f4v){0.f, 0.f, 0.f, 0.f};
#pragma unroll
    for (int kt = 0; kt < 4; ++kt) {
        s8v a = *(const s8v*)&As[rt * 16 + m][kt * 32 + q * 8];
#pragma unroll
        for (int c = 0; c < 4; ++c) {
            int ctg = ch * 4 + c;
            s8v b = *(const s8v*)&Wfrag2[(((size_t)kt * 8 + ctg) * 64 + lane) * 8];
            acc2[c] = __builtin_amdgcn_mfma_f32_16x16x32_bf16(a, b, acc2[c], 0, 0, 0);
        }
    }

    // only cols 0..47 are kept (47 classes + 1 pad col), GSTRIDE=48 rows
    u16* Gbase = (ch == 0) ? Gn : Gs;
#pragma unroll
    for (int c = 0; c < 3; ++c) {
        int col = c * 16 + m;
#pragma unroll
        for (int r = 0; r < 4; ++r) {
            int n = n0 + rt * 16 + q * 4 + r;
            if (n < n_nodes) Gbase[(size_t)n * GSTRIDE + col] = f2bf(acc2[c][r]);
        }
    }
}

// ---------------- layer-2 epilogue: gather Gn (96 B rows) + log_softmax ----------------
// One node per 64-lane wave. 16-lane groups each handle one edge: 12 active lanes
// read uint2 (8 B) covering cols 4t..4t+3 -> 4 edges per load instruction. Main loop
// strides 16 edges (4 loads/group, all unconditional via clamped addresses; lanes
// t>=12 accumulate duplicates of t=11 that are discarded at the logit stage, since
// shfl_xor(16/32) preserves t). Tail strides 4 with arithmetic masking. deg~16 ->
// typically 1 main iteration, no conditional loads anywhere.
__global__ __launch_bounds__(256) void out_kernel(const u16* __restrict__ Gn,
                                                  const u16* __restrict__ Gs,
                                                  const int* __restrict__ rowptr,
                                                  const int* __restrict__ ssrc,
                                                  const float* __restrict__ inv_deg,
                                                  const float* __restrict__ bias,
                                                  float* __restrict__ out, int n_nodes) {
    int lane = threadIdx.x & 63;
    int n = blockIdx.x * 4 + (threadIdx.x >> 6);
    if (n >= n_nodes) return;
    int grp = lane >> 4;          // edge slot within stride-4 batch
    int t = lane & 15;            // uint2 column within row (cols 4t..4t+3)
    bool act = t < 12;
    int tcl = min(t, 11);         // clamped: lanes 12..15 duplicate lane 11's load
    const uint2* Gn2 = (const uint2*)Gn;   // row = 12 uint2 (96 B)
    int e0 = rowptr[n], e1 = rowptr[n + 1];
    float f0 = 0.f, f1 = 0.f, f2 = 0.f, f3 = 0.f;
    int e = e0;
    for (; e + 15 < e1; e += 16) {
        int s[4];
#pragma unroll
        for (int j = 0; j < 4; ++j) s[j] = ssrc[e + 4 * j + grp];
        uint2 g[4];
#pragma unroll
        for (int j = 0; j < 4; ++j) g[j] = Gn2[(size_t)s[j] * 12 + tcl];
#pragma unroll
        for (int j = 0; j < 4; ++j) {
            f0 += blo(g[j].x); f1 += bhi(g[j].x);
            f2 += blo(g[j].y); f3 += bhi(g[j].y);
        }
    }
    for (; e < e1; e += 4) {
        int idx = e + grp;
        float mk = (idx < e1) ? 1.f : 0.f;
        int sc = min(idx, e1 - 1);            // e<e1 here, so e1-1 >= e0: safe
        uint2 g = Gn2[(size_t)ssrc[sc] * 12 + tcl];
        f0 = fmaf(mk, blo(g.x), f0); f1 = fmaf(mk, bhi(g.x), f1);
        f2 = fmaf(mk, blo(g.y), f2); f3 = fmaf(mk, bhi(g.y), f3);
    }
    // combine the 4 edge slots (t preserved; garbage in t>=12 stays in t>=12)
    f0 += __shfl_xor(f0, 16, 64); f0 += __shfl_xor(f0, 32, 64);
    f1 += __shfl_xor(f1, 16, 64); f1 += __shfl_xor(f1, 32, 64);
    f2 += __shfl_xor(f2, 16, 64); f2 += __shfl_xor(f2, 32, 64);
    f3 += __shfl_xor(f3, 16, 64); f3 += __shfl_xor(f3, 32, 64);

    float id = inv_deg[n];
    uint2 gs = ((const uint2*)Gs)[(size_t)n * 12 + tcl];
    int c0 = 4 * t;
    float v0 = (act && c0 + 0 < 47) ? f0 * id + blo(gs.x) + bias[c0 + 0] : -INFINITY;
    float v1 = (act && c0 + 1 < 47) ? f1 * id + bhi(gs.x) + bias[c0 + 1] : -INFINITY;
    float v2 = (act && c0 + 2 < 47) ? f2 * id + blo(gs.y) + bias[c0 + 2] : -INFINITY;
    float v3 = (act && c0 + 3 < 47) ? f3 * id + bhi(gs.y) + bias[c0 + 3] : -INFINITY;

    // softmax across the 16-lane group (every group computes the same result)
    float m = fmaxf(fmaxf(v0, v1), fmaxf(v2, v3));
#pragma unroll
    for (int off = 8; off >= 1; off >>= 1)
        m = fmaxf(m, __shfl_xor(m, off, 16));
    float s = ((v0 != -INFINITY) ? __expf(v0 - m) : 0.f) +
              ((v1 != -INFINITY) ? __expf(v1 - m) : 0.f) +
              ((v2 != -INFINITY) ? __expf(v2 - m) : 0.f) +
              ((v3 != -INFINITY) ? __expf(v3 - m) : 0.f);
#pragma unroll
    for (int off = 8; off >= 1; off >>= 1)
        s += __shfl_xor(s, off, 16);
    float ls = __logf(s);
    if (grp == 0 && act) {
        float* o = &out[(size_t)n * 47];
        if (c0 + 0 < 47) o[c0 + 0] = v0 - m - ls;
        if (c0 + 1 < 47) o[c0 + 1] = v1 - m - ls;
        if (c0 + 2 < 47) o[c0 + 2] = v2 - m - ls;
        if (c0 + 3 < 47) o[c0 + 3] = v3 - m - ls;
    }
}

// ---------------- launch ----------------

extern "C" void kernel_launch(void* const* d_in, const int* in_sizes, int n_in,
                              void* d_out, int out_size, void* d_ws, size_t ws_size,
                              hipStream_t stream) {
    const float* x   = (const float*)d_in[0];
    const int*   src = (const int*)d_in[1];
    const int*   dst = (const int*)d_in[2];
    const float* Wl0 = (const float*)d_in[3];
    const float* bl0 = (const float*)d_in[4];
    const float* Wr0 = (const float*)d_in[5];
    const float* Wl1 = (const float*)d_in[6];
    const float* bl1 = (const float*)d_in[7];
    const float* Wr1 = (const float*)d_in[8];
    const float* Wl2 = (const float*)d_in[9];
    const float* bl2 = (const float*)d_in[10];
    const float* Wr2 = (const float*)d_in[11];
    float* out = (float*)d_out;

    int N = in_sizes[0] / 128;
    int E = in_sizes[1];
    int nBuckets = (N + 255) >> BUCKET_SHIFT;

    char* ws = (char*)d_ws;
    size_t off = 0;
    auto alloc = [&](size_t bytes) -> char* {
        char* p = ws + off;
        off += (bytes + 255) & ~(size_t)255;
        return p;
    };
    int*   rowptr = (int*)alloc((size_t)(N + 1) * 4);
    float* invd   = (float*)alloc((size_t)N * 4);
    int*   ssrc   = (int*)alloc((size_t)E * 4);
    u16*   xb     = (u16*)alloc((size_t)N * 128 * 2);   // layer0 in, layer1 out
    u16*   h1     = (u16*)alloc((size_t)N * 128 * 2);   // layer0 out, layer1 in
    u16*   Gn     = (u16*)alloc((size_t)N * GSTRIDE * 2);  // neighbor projection (layer 2)
    u16*   Gs     = (u16*)alloc((size_t)N * GSTRIDE * 2);  // self projection (layer 2)
    int*   bucketCnt  = (int*)alloc(512 * 4);
    int*   bucketBase = (int*)alloc(520 * 4);
    int*   gcur   = (int*)alloc(512 * 4);
    u16*   wf0    = (u16*)alloc(32768 * 2);
    u16*   wf1    = (u16*)alloc(32768 * 2);
    u16*   wf2    = (u16*)alloc(16384 * 2);

    // interm (E uints = 6.4 MB) aliases Gn+Gs (19.2 MB): consumed by bucket_build
    // long before sage_layer_mfma_g writes Gn/Gs.
    unsigned* interm = (unsigned*)Gn;

    int nChunks = (E + CHUNK - 1) / CHUNK;

    hipMemsetAsync(bucketCnt, 0, 512 * 4, stream);
    bucket_count_kernel<<<nChunks, 256, 0, stream>>>(dst, bucketCnt, E, nBuckets);
    scan_buckets_kernel<<<1, 512, 0, stream>>>(bucketCnt, bucketBase, gcur, nBuckets);
    bucket_scatter_kernel<<<nChunks, 256, 0, stream>>>(src, dst, gcur, interm, E, nBuckets);
    bucket_build_kernel<<<nBuckets, 256, 0, stream>>>(interm, bucketBase, rowptr, invd,
                                                      ssrc, N);
    long total8 = (long)N * 16;  // N*128/8
    convert_kernel<<<(int)((total8 + 255) / 256), 256, 0, stream>>>(x, xb, total8);
    pack_all_kernel<<<320, 256, 0, stream>>>(Wl0, Wr0, Wl1, Wr1, Wl2, Wr2, wf0, wf1, wf2);

    int gemmGrid = (N + 31) / 32;

    // layer 0: xb -> h1 (fused gather-agg + MFMA)
    sage_layer_mfma<<<gemmGrid, 256, 0, stream>>>((const uint2*)xb, rowptr, ssrc, invd,
                                                  wf0, bl0, h1, N);
    // layer 1 + layer-2 projection fused: h1 -> [Gn|Gs], h2 never hits HBM
    sage_layer_mfma_g<<<gemmGrid, 256, 0, stream>>>((const uint2*)h1, rowptr, ssrc, invd,
                                                    wf1, bl1, wf2, Gn, Gs, N);
    // layer 2 epilogue: 96 B line gather + log_softmax
    out_kernel<<<(N + 3) / 4, 256, 0, stream>>>(Gn, Gs, rowptr, ssrc, invd, bl2, out, N);
}